// Round 13
// baseline (58.044 us; speedup 1.0000x reference)
//
#include <hip/hip_runtime.h>
#include <math.h>

#define BATCH 32
#define NSAMP 262144
#define NKNOT 256
#define EPSV  0.001f
#define CH    16                  // samples per chunk = 64 B = one cache line
#define CPB   256                 // chunks per agg-block (= k_agg threads)
#define NCROW (NSAMP / CH)        // 16384 chunks per row
#define BPR   (NCROW / CPB)       // 64 agg-blocks per row (one wave scans it)
#define NB    (BATCH * NCROW / CPB)  // 2048 agg-blocks
#define TC    (BATCH * NCROW)     // 524288 chunks total
#define NWAVE (CPB / 64)          // 4 waves per block

__device__ __forceinline__ float fast_tanh(float x) {
    // tanh(x) = 1 - 2/(exp(2x)+1); branch-free, ~1e-7 abs error
    float e = __expf(2.0f * x);
    float r = __builtin_amdgcn_rcpf(e + 1.0f);
    return fmaf(-2.0f, r, 1.0f);
}

// ---------------------------------------------------------------------------
// Kernel 1 (R11-identical): per-chunk exclusive in-block prefix C + block G
// ---------------------------------------------------------------------------
__global__ __launch_bounds__(256, 4) void k_agg(
    const float* __restrict__ x,
    const float* __restrict__ cl,     // [BATCH][NKNOT][5]
    float* __restrict__ Cb,           // [6][TC]
    float* __restrict__ G)            // [6][NB]
{
    __shared__ float wag[NWAVE][6];
    const int tid = threadIdx.x;
    const int b = blockIdx.x;
    const int lane = tid & 63, wid = tid >> 6;

    int chunk = b * CPB + tid;
    const float4* xp = (const float4*)(x + (size_t)chunk * CH);

    // knot coefficients (channels 0,1)
    int r = chunk >> 14;                 // / NCROW
    int c = chunk & (NCROW - 1);
    const float scale = 255.0f / 262143.0f;
    float pos0 = (float)(c * CH) * scale;
    float fiA = floorf(pos0);
    int idxA = (int)fiA;
    float w0v = pos0 - fiA;
    const float* kb = cl + (size_t)r * NKNOT * 5;
    int i1 = min(idxA + 1, NKNOT - 1);
    int i2 = min(idxA + 2, NKNOT - 1);
    float k00 = kb[idxA*5+0], k01 = kb[i1*5+0], k02 = kb[i2*5+0];
    float k10 = kb[idxA*5+1], k11 = kb[i1*5+1], k12 = kb[i2*5+1];
    float d0A = k01-k00, d0B = k02-k01;
    float d1A = k11-k10, d1B = k12-k11;

    // build per-chunk affine map  s_end = M s_start + v (consume x inline)
    const float stab = 1.0f - EPSV, stab2 = 2.0f * stab;
    float p1 = 0.f, p2 = 0.f, A1 = 1.f, A2 = 0.f, B1 = 0.f, B2 = 1.f;
    #pragma unroll
    for (int v4 = 0; v4 < 4; ++v4) {
        float4 xq = xp[v4];
        #pragma unroll
        for (int q = 0; q < 4; ++q) {
            int j = v4 * 4 + q;
            float w = fmaf((float)j, scale, w0v);
            bool sel = w >= 1.0f;
            float wu = sel ? w - 1.0f : w;
            float l0 = fmaf(wu, sel ? d0B : d0A, sel ? k01 : k00);
            float l1 = fmaf(wu, sel ? d1B : d1A, sel ? k11 : k10);
            float a1 = stab2 * fast_tanh(l0);
            float a1a = fabsf(a1);
            float a2 = 0.5f * fmaf((2.0f - a1a) * stab, fast_tanh(l1), a1a);
            float p  = fmaf(-a2, p2, (&xq.x)[q]);  p = fmaf(-a1, p1, p);
            float hA = fmaf(-a1, A1, -a2 * A2);
            float hB = fmaf(-a1, B1, -a2 * B2);
            p2 = p1; p1 = p;
            A2 = A1; A1 = hA;
            B2 = B1; B1 = hB;
        }
    }
    float L00 = A1, L01 = B1, L10 = A2, L11 = B2, Lv0 = p1, Lv1 = p2;

    // wave-inclusive scan (compose later ∘ earlier)
    #pragma unroll
    for (int d = 1; d < 64; d <<= 1) {
        float o00 = __shfl_up(L00, d), o01 = __shfl_up(L01, d);
        float o10 = __shfl_up(L10, d), o11 = __shfl_up(L11, d);
        float ov0 = __shfl_up(Lv0, d), ov1 = __shfl_up(Lv1, d);
        if (lane >= d) {
            float n00 = L00 * o00 + L01 * o10;
            float n01 = L00 * o01 + L01 * o11;
            float n10 = L10 * o00 + L11 * o10;
            float n11 = L10 * o01 + L11 * o11;
            float nv0 = fmaf(L00, ov0, fmaf(L01, ov1, Lv0));
            float nv1 = fmaf(L10, ov0, fmaf(L11, ov1, Lv1));
            L00 = n00; L01 = n01; L10 = n10; L11 = n11; Lv0 = nv0; Lv1 = nv1;
        }
    }
    if (lane == 63) {
        wag[wid][0] = L00; wag[wid][1] = L01; wag[wid][2] = L10;
        wag[wid][3] = L11; wag[wid][4] = Lv0; wag[wid][5] = Lv1;
    }
    __syncthreads();

    // P = compose of earlier waves' aggregates
    float P00 = 1.f, P01 = 0.f, P10 = 0.f, P11 = 1.f, Pv0 = 0.f, Pv1 = 0.f;
    for (int w2 = 0; w2 < wid; ++w2) {
        float a00 = wag[w2][0], a01 = wag[w2][1], a10 = wag[w2][2];
        float a11 = wag[w2][3], av0 = wag[w2][4], av1 = wag[w2][5];
        float n00 = a00 * P00 + a01 * P10;
        float n01 = a00 * P01 + a01 * P11;
        float n10 = a10 * P00 + a11 * P10;
        float n11 = a10 * P01 + a11 * P11;
        float nv0 = fmaf(a00, Pv0, fmaf(a01, Pv1, av0));
        float nv1 = fmaf(a10, Pv0, fmaf(a11, Pv1, av1));
        P00 = n00; P01 = n01; P10 = n10; P11 = n11; Pv0 = nv0; Pv1 = nv1;
    }
    // in-wave exclusive E; C = E ∘ P (exclusive prefix from block start)
    float E00 = __shfl_up(L00, 1), E01 = __shfl_up(L01, 1);
    float E10 = __shfl_up(L10, 1), E11 = __shfl_up(L11, 1);
    float Ev0 = __shfl_up(Lv0, 1), Ev1 = __shfl_up(Lv1, 1);
    if (lane == 0) { E00 = 1.f; E01 = 0.f; E10 = 0.f; E11 = 1.f; Ev0 = 0.f; Ev1 = 0.f; }
    Cb[0*TC + chunk] = E00 * P00 + E01 * P10;
    Cb[1*TC + chunk] = E00 * P01 + E01 * P11;
    Cb[2*TC + chunk] = E10 * P00 + E11 * P10;
    Cb[3*TC + chunk] = E10 * P01 + E11 * P11;
    Cb[4*TC + chunk] = fmaf(E00, Pv0, fmaf(E01, Pv1, Ev0));
    Cb[5*TC + chunk] = fmaf(E10, Pv0, fmaf(E11, Pv1, Ev1));

    // block aggregate G = L(tid=255) ∘ P
    if (tid == CPB - 1) {
        G[0*NB + b] = L00 * P00 + L01 * P10;
        G[1*NB + b] = L00 * P01 + L01 * P11;
        G[2*NB + b] = L10 * P00 + L11 * P10;
        G[3*NB + b] = L10 * P01 + L11 * P11;
        G[4*NB + b] = fmaf(L00, Pv0, fmaf(L01, Pv1, Lv0));
        G[5*NB + b] = fmaf(L10, Pv0, fmaf(L11, Pv1, Lv1));
    }
}

// ---------------------------------------------------------------------------
// Kernel 2: 256 thr × 2 chunks (ILP 2); per-wave redundant row-scan of G;
// no barriers, no LDS.
// ---------------------------------------------------------------------------
__global__ __launch_bounds__(256, 4) void k_apply(
    const float* __restrict__ x,
    const float* __restrict__ cl,
    const float* __restrict__ Cb,     // [6][TC]
    const float* __restrict__ G,      // [6][NB]
    float* __restrict__ out)
{
    const int tid = threadIdx.x;
    const int b = blockIdx.x;         // 512-chunk apply-block
    const int lane = tid & 63;

    // every wave: inclusive scan of this row's 64 agg-block aggregates
    const int rowFirstAgg = (b >> 5) * BPR;    // 32 apply-blocks per row
    {
        int k = rowFirstAgg + lane;
        float A00 = G[0*NB + k], A01 = G[1*NB + k], A10 = G[2*NB + k];
        float A11 = G[3*NB + k], Av0 = G[4*NB + k], Av1 = G[5*NB + k];
        #pragma unroll
        for (int d = 1; d < 64; d <<= 1) {
            float o00 = __shfl_up(A00, d), o01 = __shfl_up(A01, d);
            float o10 = __shfl_up(A10, d), o11 = __shfl_up(A11, d);
            float ov0 = __shfl_up(Av0, d), ov1 = __shfl_up(Av1, d);
            if (lane >= d) {
                float n00 = A00 * o00 + A01 * o10;
                float n01 = A00 * o01 + A01 * o11;
                float n10 = A10 * o00 + A11 * o10;
                float n11 = A10 * o01 + A11 * o11;
                float nv0 = fmaf(A00, ov0, fmaf(A01, ov1, Av0));
                float nv1 = fmaf(A10, ov0, fmaf(A11, ov1, Av1));
                A00 = n00; A01 = n01; A10 = n10; A11 = n11; Av0 = nv0; Av1 = nv1;
            }
        }
        // this wave's threads all belong to the same agg-block (tid>>7 uniform)
        int idxInRow = ((b & 31) << 1) + (tid >> 7);
        float t0 = __shfl(Av0, idxInRow - 1);       // uniform lane index
        float t1 = __shfl(Av1, idxInRow - 1);
        Av0 = (idxInRow > 0) ? t0 : 0.f;
        Av1 = (idxInRow > 0) ? t1 : 0.f;
        // stash row-prefix state in A00/A01 names for reuse below
        A00 = Av0; A01 = Av1;
        // fallthrough via variables:
        // (compiler keeps these live; renamed below)
        #define S0_ A00
        #define S1_ A01
        // chunk pair setup follows
        const int chunk0 = b * 512 + 2 * tid;       // even; pair in same agg-block
        // --- knot coefficients for both chunks ---
        const float scale = 255.0f / 262143.0f;
        int r = chunk0 >> 14;
        const float* kb = cl + (size_t)r * NKNOT * 5;

        int cA = chunk0 & (NCROW - 1);
        float posA = (float)(cA * CH) * scale;
        float fiA = floorf(posA);
        int iA0 = (int)fiA;
        float wA0 = posA - fiA;
        int iA1 = min(iA0 + 1, NKNOT - 1), iA2 = min(iA0 + 2, NKNOT - 1);
        float ak0[5], ak1[5], ak2[5];
        #pragma unroll
        for (int ch2 = 0; ch2 < 5; ++ch2) {
            ak0[ch2] = kb[iA0*5+ch2]; ak1[ch2] = kb[iA1*5+ch2]; ak2[ch2] = kb[iA2*5+ch2];
        }
        float posB = (float)((cA + 1) * CH) * scale;
        float fiB = floorf(posB);
        int iB0 = (int)fiB;
        float wB0 = posB - fiB;
        int iB1 = min(iB0 + 1, NKNOT - 1), iB2 = min(iB0 + 2, NKNOT - 1);
        float bk0[5], bk1[5], bk2[5];
        #pragma unroll
        for (int ch2 = 0; ch2 < 5; ++ch2) {
            bk0[ch2] = kb[iB0*5+ch2]; bk1[ch2] = kb[iB1*5+ch2]; bk2[ch2] = kb[iB2*5+ch2];
        }

        // --- C for both chunks (float2 loads) -> start states ---
        float2 c0 = *(const float2*)&Cb[0*TC + chunk0];
        float2 c1 = *(const float2*)&Cb[1*TC + chunk0];
        float2 c2 = *(const float2*)&Cb[2*TC + chunk0];
        float2 c3 = *(const float2*)&Cb[3*TC + chunk0];
        float2 c4 = *(const float2*)&Cb[4*TC + chunk0];
        float2 c5 = *(const float2*)&Cb[5*TC + chunk0];
        float yA1 = fmaf(c0.x, S0_, fmaf(c1.x, S1_, c4.x));
        float yA2 = fmaf(c2.x, S0_, fmaf(c3.x, S1_, c5.x));
        float yB1 = fmaf(c0.y, S0_, fmaf(c1.y, S1_, c4.y));
        float yB2 = fmaf(c2.y, S0_, fmaf(c3.y, S1_, c5.y));

        // --- two interleaved apply+FIR chains ---
        const float stab = 1.0f - EPSV, stab2 = 2.0f * stab;
        const float4* xp = (const float4*)(x + (size_t)chunk0 * CH);
        float4* op = (float4*)(out + (size_t)chunk0 * CH);
        #pragma unroll
        for (int v4 = 0; v4 < 4; ++v4) {
            float4 xqa = xp[v4];
            float4 xqb = xp[4 + v4];
            float4 ova, ovb;
            #pragma unroll
            for (int q = 0; q < 4; ++q) {
                int j = v4 * 4 + q;
                // chunk A
                {
                    float w = fmaf((float)j, scale, wA0);
                    bool sel = w >= 1.0f;
                    float wu = sel ? w - 1.0f : w;
                    float l0 = fmaf(wu, sel ? ak2[0]-ak1[0] : ak1[0]-ak0[0], sel ? ak1[0] : ak0[0]);
                    float l1 = fmaf(wu, sel ? ak2[1]-ak1[1] : ak1[1]-ak0[1], sel ? ak1[1] : ak0[1]);
                    float b0 = fmaf(wu, sel ? ak2[2]-ak1[2] : ak1[2]-ak0[2], sel ? ak1[2] : ak0[2]);
                    float b1c= fmaf(wu, sel ? ak2[3]-ak1[3] : ak1[3]-ak0[3], sel ? ak1[3] : ak0[3]);
                    float b2c= fmaf(wu, sel ? ak2[4]-ak1[4] : ak1[4]-ak0[4], sel ? ak1[4] : ak0[4]);
                    float a1 = stab2 * fast_tanh(l0);
                    float a1a = fabsf(a1);
                    float a2 = 0.5f * fmaf((2.0f - a1a) * stab, fast_tanh(l1), a1a);
                    float y = fmaf(-a2, yA2, (&xqa.x)[q]);  y = fmaf(-a1, yA1, y);
                    (&ova.x)[q] = fmaf(b0, y, fmaf(b1c, yA1, b2c * yA2));
                    yA2 = yA1; yA1 = y;
                }
                // chunk B (independent chain)
                {
                    float w = fmaf((float)j, scale, wB0);
                    bool sel = w >= 1.0f;
                    float wu = sel ? w - 1.0f : w;
                    float l0 = fmaf(wu, sel ? bk2[0]-bk1[0] : bk1[0]-bk0[0], sel ? bk1[0] : bk0[0]);
                    float l1 = fmaf(wu, sel ? bk2[1]-bk1[1] : bk1[1]-bk0[1], sel ? bk1[1] : bk0[1]);
                    float b0 = fmaf(wu, sel ? bk2[2]-bk1[2] : bk1[2]-bk0[2], sel ? bk1[2] : bk0[2]);
                    float b1c= fmaf(wu, sel ? bk2[3]-bk1[3] : bk1[3]-bk0[3], sel ? bk1[3] : bk0[3]);
                    float b2c= fmaf(wu, sel ? bk2[4]-bk1[4] : bk1[4]-bk0[4], sel ? bk1[4] : bk0[4]);
                    float a1 = stab2 * fast_tanh(l0);
                    float a1a = fabsf(a1);
                    float a2 = 0.5f * fmaf((2.0f - a1a) * stab, fast_tanh(l1), a1a);
                    float y = fmaf(-a2, yB2, (&xqb.x)[q]);  y = fmaf(-a1, yB1, y);
                    (&ovb.x)[q] = fmaf(b0, y, fmaf(b1c, yB1, b2c * yB2));
                    yB2 = yB1; yB1 = y;
                }
            }
            op[v4] = ova;
            op[4 + v4] = ovb;
        }
        #undef S0_
        #undef S1_
    }
}

extern "C" void kernel_launch(void* const* d_in, const int* in_sizes, int n_in,
                              void* d_out, int out_size, void* d_ws, size_t ws_size,
                              hipStream_t stream) {
    const float* x  = (const float*)d_in[0];   // [32][262144]
    const float* cl = (const float*)d_in[1];   // [32][256][5]
    float* out = (float*)d_out;
    float* Cb = (float*)d_ws;                  // [6][TC] = 12.6 MB
    float* G  = Cb + (size_t)6 * TC;           // [6][NB] = 48 KB

    hipLaunchKernelGGL(k_agg,   dim3(NB),     dim3(256), 0, stream, x, cl, Cb, G);
    hipLaunchKernelGGL(k_apply, dim3(TC/512), dim3(256), 0, stream, x, cl, Cb, G, out);
}

// Round 14
// 46.852 us; speedup vs baseline: 1.2389x; 1.2389x over previous
//
#include <hip/hip_runtime.h>
#include <math.h>

#define BATCH 32
#define NSAMP 262144
#define NKNOT 256
#define EPSV  0.001f
#define CH    16                  // samples per chunk = 64 B = one cache line
#define CPB   256                 // chunks per agg-block (= k_agg threads)
#define NCROW (NSAMP / CH)        // 16384 chunks per row
#define BPR   (NCROW / CPB)       // 64 agg-blocks per row (one wave scans it)
#define NB    (BATCH * NCROW / CPB)  // 2048 agg-blocks
#define TC    (BATCH * NCROW)     // 524288 chunks total
#define NWAVE (CPB / 64)          // 4 waves per block

__device__ __forceinline__ float fast_tanh(float x) {
    // tanh(x) = 1 - 2/(exp(2x)+1); branch-free, ~1e-7 abs error
    float e = __expf(2.0f * x);
    float r = __builtin_amdgcn_rcpf(e + 1.0f);
    return fmaf(-2.0f, r, 1.0f);
}

// ---------------------------------------------------------------------------
// Kernel 1 (R11-identical, proven absmax 40): per-chunk exclusive prefix C + G
// ---------------------------------------------------------------------------
__global__ __launch_bounds__(256, 4) void k_agg(
    const float* __restrict__ x,
    const float* __restrict__ cl,     // [BATCH][NKNOT][5]
    float* __restrict__ Cb,           // [6][TC]
    float* __restrict__ G)            // [6][NB]
{
    __shared__ float wag[NWAVE][6];
    const int tid = threadIdx.x;
    const int b = blockIdx.x;
    const int lane = tid & 63, wid = tid >> 6;

    int chunk = b * CPB + tid;
    const float4* xp = (const float4*)(x + (size_t)chunk * CH);

    // knot coefficients (channels 0,1)
    int r = chunk >> 14;                 // / NCROW
    int c = chunk & (NCROW - 1);
    const float scale = 255.0f / 262143.0f;
    float pos0 = (float)(c * CH) * scale;
    float fiA = floorf(pos0);
    int idxA = (int)fiA;
    float w0v = pos0 - fiA;
    const float* kb = cl + (size_t)r * NKNOT * 5;
    int i1 = min(idxA + 1, NKNOT - 1);
    int i2 = min(idxA + 2, NKNOT - 1);
    float k00 = kb[idxA*5+0], k01 = kb[i1*5+0], k02 = kb[i2*5+0];
    float k10 = kb[idxA*5+1], k11 = kb[i1*5+1], k12 = kb[i2*5+1];
    float d0A = k01-k00, d0B = k02-k01;
    float d1A = k11-k10, d1B = k12-k11;

    // build per-chunk affine map  s_end = M s_start + v (consume x inline)
    const float stab = 1.0f - EPSV, stab2 = 2.0f * stab;
    float p1 = 0.f, p2 = 0.f, A1 = 1.f, A2 = 0.f, B1 = 0.f, B2 = 1.f;
    #pragma unroll
    for (int v4 = 0; v4 < 4; ++v4) {
        float4 xq = xp[v4];
        #pragma unroll
        for (int q = 0; q < 4; ++q) {
            int j = v4 * 4 + q;
            float w = fmaf((float)j, scale, w0v);
            bool sel = w >= 1.0f;
            float wu = sel ? w - 1.0f : w;
            float l0 = fmaf(wu, sel ? d0B : d0A, sel ? k01 : k00);
            float l1 = fmaf(wu, sel ? d1B : d1A, sel ? k11 : k10);
            float a1 = stab2 * fast_tanh(l0);
            float a1a = fabsf(a1);
            float a2 = 0.5f * fmaf((2.0f - a1a) * stab, fast_tanh(l1), a1a);
            float p  = fmaf(-a2, p2, (&xq.x)[q]);  p = fmaf(-a1, p1, p);
            float hA = fmaf(-a1, A1, -a2 * A2);
            float hB = fmaf(-a1, B1, -a2 * B2);
            p2 = p1; p1 = p;
            A2 = A1; A1 = hA;
            B2 = B1; B1 = hB;
        }
    }
    float L00 = A1, L01 = B1, L10 = A2, L11 = B2, Lv0 = p1, Lv1 = p2;

    // wave-inclusive scan (compose later ∘ earlier)
    #pragma unroll
    for (int d = 1; d < 64; d <<= 1) {
        float o00 = __shfl_up(L00, d), o01 = __shfl_up(L01, d);
        float o10 = __shfl_up(L10, d), o11 = __shfl_up(L11, d);
        float ov0 = __shfl_up(Lv0, d), ov1 = __shfl_up(Lv1, d);
        if (lane >= d) {
            float n00 = L00 * o00 + L01 * o10;
            float n01 = L00 * o01 + L01 * o11;
            float n10 = L10 * o00 + L11 * o10;
            float n11 = L10 * o01 + L11 * o11;
            float nv0 = fmaf(L00, ov0, fmaf(L01, ov1, Lv0));
            float nv1 = fmaf(L10, ov0, fmaf(L11, ov1, Lv1));
            L00 = n00; L01 = n01; L10 = n10; L11 = n11; Lv0 = nv0; Lv1 = nv1;
        }
    }
    if (lane == 63) {
        wag[wid][0] = L00; wag[wid][1] = L01; wag[wid][2] = L10;
        wag[wid][3] = L11; wag[wid][4] = Lv0; wag[wid][5] = Lv1;
    }
    __syncthreads();

    // P = compose of earlier waves' aggregates
    float P00 = 1.f, P01 = 0.f, P10 = 0.f, P11 = 1.f, Pv0 = 0.f, Pv1 = 0.f;
    for (int w2 = 0; w2 < wid; ++w2) {
        float a00 = wag[w2][0], a01 = wag[w2][1], a10 = wag[w2][2];
        float a11 = wag[w2][3], av0 = wag[w2][4], av1 = wag[w2][5];
        float n00 = a00 * P00 + a01 * P10;
        float n01 = a00 * P01 + a01 * P11;
        float n10 = a10 * P00 + a11 * P10;
        float n11 = a10 * P01 + a11 * P11;
        float nv0 = fmaf(a00, Pv0, fmaf(a01, Pv1, av0));
        float nv1 = fmaf(a10, Pv0, fmaf(a11, Pv1, av1));
        P00 = n00; P01 = n01; P10 = n10; P11 = n11; Pv0 = nv0; Pv1 = nv1;
    }
    // in-wave exclusive E; C = E ∘ P (exclusive prefix from block start)
    float E00 = __shfl_up(L00, 1), E01 = __shfl_up(L01, 1);
    float E10 = __shfl_up(L10, 1), E11 = __shfl_up(L11, 1);
    float Ev0 = __shfl_up(Lv0, 1), Ev1 = __shfl_up(Lv1, 1);
    if (lane == 0) { E00 = 1.f; E01 = 0.f; E10 = 0.f; E11 = 1.f; Ev0 = 0.f; Ev1 = 0.f; }
    Cb[0*TC + chunk] = E00 * P00 + E01 * P10;
    Cb[1*TC + chunk] = E00 * P01 + E01 * P11;
    Cb[2*TC + chunk] = E10 * P00 + E11 * P10;
    Cb[3*TC + chunk] = E10 * P01 + E11 * P11;
    Cb[4*TC + chunk] = fmaf(E00, Pv0, fmaf(E01, Pv1, Ev0));
    Cb[5*TC + chunk] = fmaf(E10, Pv0, fmaf(E11, Pv1, Ev1));

    // block aggregate G = L(tid=255) ∘ P
    if (tid == CPB - 1) {
        G[0*NB + b] = L00 * P00 + L01 * P10;
        G[1*NB + b] = L00 * P01 + L01 * P11;
        G[2*NB + b] = L10 * P00 + L11 * P10;
        G[3*NB + b] = L10 * P01 + L11 * P11;
        G[4*NB + b] = fmaf(L00, Pv0, fmaf(L01, Pv1, Lv0));
        G[5*NB + b] = fmaf(L10, Pv0, fmaf(L11, Pv1, Lv1));
    }
}

// ---------------------------------------------------------------------------
// Kernel 2: 256 thr × 2 adjacent chunks sharing ONE 3-knot window (15 regs);
// per-wave redundant row-scan of G; no barriers, no LDS.
// ---------------------------------------------------------------------------
__global__ __launch_bounds__(256, 3) void k_apply(
    const float* __restrict__ x,
    const float* __restrict__ cl,
    const float* __restrict__ Cb,     // [6][TC]
    const float* __restrict__ G,      // [6][NB]
    float* __restrict__ out)
{
    const int tid = threadIdx.x;
    const int b = blockIdx.x;         // 512-chunk apply-block
    const int lane = tid & 63;

    // every wave: inclusive scan of this row's 64 agg-block aggregates
    const int rowFirstAgg = (b >> 5) * BPR;    // 32 apply-blocks per row
    int kk = rowFirstAgg + lane;
    float A00 = G[0*NB + kk], A01 = G[1*NB + kk], A10 = G[2*NB + kk];
    float A11 = G[3*NB + kk], Av0 = G[4*NB + kk], Av1 = G[5*NB + kk];
    #pragma unroll
    for (int d = 1; d < 64; d <<= 1) {
        float o00 = __shfl_up(A00, d), o01 = __shfl_up(A01, d);
        float o10 = __shfl_up(A10, d), o11 = __shfl_up(A11, d);
        float ov0 = __shfl_up(Av0, d), ov1 = __shfl_up(Av1, d);
        if (lane >= d) {
            float n00 = A00 * o00 + A01 * o10;
            float n01 = A00 * o01 + A01 * o11;
            float n10 = A10 * o00 + A11 * o10;
            float n11 = A10 * o01 + A11 * o11;
            float nv0 = fmaf(A00, ov0, fmaf(A01, ov1, Av0));
            float nv1 = fmaf(A10, ov0, fmaf(A11, ov1, Av1));
            A00 = n00; A01 = n01; A10 = n10; A11 = n11; Av0 = nv0; Av1 = nv1;
        }
    }
    // wave-uniform prefix pick: tid>>7 is uniform within a wave
    int idxInRow = ((b & 31) << 1) + (tid >> 7);
    int src = (idxInRow > 0) ? idxInRow - 1 : 0;
    float s0 = __shfl(Av0, src);
    float s1 = __shfl(Av1, src);
    if (idxInRow == 0) { s0 = 0.f; s1 = 0.f; }

    // chunk pair (2t, 2t+1) shares one 3-knot window (pair spans <=2 segments)
    const int chunk0 = b * 512 + 2 * tid;
    const float scale = 255.0f / 262143.0f;
    int r = chunk0 >> 14;
    const float* kb = cl + (size_t)r * NKNOT * 5;
    int cA = chunk0 & (NCROW - 1);
    float posA = (float)(cA * CH) * scale;
    float fiA = floorf(posA);
    int i0 = (int)fiA;
    float wA0 = posA - fiA;
    int i1 = min(i0 + 1, NKNOT - 1), i2 = min(i0 + 2, NKNOT - 1);
    float k00 = kb[i0*5+0], k01 = kb[i1*5+0], k02 = kb[i2*5+0];
    float k10 = kb[i0*5+1], k11 = kb[i1*5+1], k12 = kb[i2*5+1];
    float k20 = kb[i0*5+2], k21 = kb[i1*5+2], k22 = kb[i2*5+2];
    float k30 = kb[i0*5+3], k31 = kb[i1*5+3], k32 = kb[i2*5+3];
    float k40 = kb[i0*5+4], k41 = kb[i1*5+4], k42 = kb[i2*5+4];

    // C for both chunks (float2 loads) -> start states
    float2 c0 = *(const float2*)&Cb[0*TC + chunk0];
    float2 c1 = *(const float2*)&Cb[1*TC + chunk0];
    float2 c2 = *(const float2*)&Cb[2*TC + chunk0];
    float2 c3 = *(const float2*)&Cb[3*TC + chunk0];
    float2 c4 = *(const float2*)&Cb[4*TC + chunk0];
    float2 c5 = *(const float2*)&Cb[5*TC + chunk0];
    float yA1 = fmaf(c0.x, s0, fmaf(c1.x, s1, c4.x));
    float yA2 = fmaf(c2.x, s0, fmaf(c3.x, s1, c5.x));
    float yB1 = fmaf(c0.y, s0, fmaf(c1.y, s1, c4.y));
    float yB2 = fmaf(c2.y, s0, fmaf(c3.y, s1, c5.y));

    // two interleaved apply+FIR chains over the shared knot window
    const float stab = 1.0f - EPSV, stab2 = 2.0f * stab;
    const float4* xp = (const float4*)(x + (size_t)chunk0 * CH);
    float4* op = (float4*)(out + (size_t)chunk0 * CH);
    #pragma unroll
    for (int v4 = 0; v4 < 4; ++v4) {
        float4 xqa = xp[v4];
        float4 xqb = xp[4 + v4];
        float4 ova, ovb;
        #pragma unroll
        for (int q = 0; q < 4; ++q) {
            int j = v4 * 4 + q;
            // chunk A sample j
            {
                float w = fmaf((float)j, scale, wA0);
                bool sel = w >= 1.0f;
                float wu = sel ? w - 1.0f : w;
                float l0 = fmaf(wu, sel ? k02-k01 : k01-k00, sel ? k01 : k00);
                float l1 = fmaf(wu, sel ? k12-k11 : k11-k10, sel ? k11 : k10);
                float b0 = fmaf(wu, sel ? k22-k21 : k21-k20, sel ? k21 : k20);
                float b1c= fmaf(wu, sel ? k32-k31 : k31-k30, sel ? k31 : k30);
                float b2c= fmaf(wu, sel ? k42-k41 : k41-k40, sel ? k41 : k40);
                float a1 = stab2 * fast_tanh(l0);
                float a1a = fabsf(a1);
                float a2 = 0.5f * fmaf((2.0f - a1a) * stab, fast_tanh(l1), a1a);
                float y = fmaf(-a2, yA2, (&xqa.x)[q]);  y = fmaf(-a1, yA1, y);
                (&ova.x)[q] = fmaf(b0, y, fmaf(b1c, yA1, b2c * yA2));
                yA2 = yA1; yA1 = y;
            }
            // chunk B sample j (independent chain, same knot window, j+16)
            {
                float w = fmaf((float)(j + CH), scale, wA0);
                bool sel = w >= 1.0f;
                float wu = sel ? w - 1.0f : w;
                float l0 = fmaf(wu, sel ? k02-k01 : k01-k00, sel ? k01 : k00);
                float l1 = fmaf(wu, sel ? k12-k11 : k11-k10, sel ? k11 : k10);
                float b0 = fmaf(wu, sel ? k22-k21 : k21-k20, sel ? k21 : k20);
                float b1c= fmaf(wu, sel ? k32-k31 : k31-k30, sel ? k31 : k30);
                float b2c= fmaf(wu, sel ? k42-k41 : k41-k40, sel ? k41 : k40);
                float a1 = stab2 * fast_tanh(l0);
                float a1a = fabsf(a1);
                float a2 = 0.5f * fmaf((2.0f - a1a) * stab, fast_tanh(l1), a1a);
                float y = fmaf(-a2, yB2, (&xqb.x)[q]);  y = fmaf(-a1, yB1, y);
                (&ovb.x)[q] = fmaf(b0, y, fmaf(b1c, yB1, b2c * yB2));
                yB2 = yB1; yB1 = y;
            }
        }
        op[v4] = ova;
        op[4 + v4] = ovb;
    }
}

extern "C" void kernel_launch(void* const* d_in, const int* in_sizes, int n_in,
                              void* d_out, int out_size, void* d_ws, size_t ws_size,
                              hipStream_t stream) {
    const float* x  = (const float*)d_in[0];   // [32][262144]
    const float* cl = (const float*)d_in[1];   // [32][256][5]
    float* out = (float*)d_out;
    float* Cb = (float*)d_ws;                  // [6][TC] = 12.6 MB
    float* G  = Cb + (size_t)6 * TC;           // [6][NB] = 48 KB

    hipLaunchKernelGGL(k_agg,   dim3(NB),     dim3(256), 0, stream, x, cl, Cb, G);
    hipLaunchKernelGGL(k_apply, dim3(TC/512), dim3(256), 0, stream, x, cl, Cb, G, out);
}

// Round 15
// 40.781 us; speedup vs baseline: 1.4233x; 1.1489x over previous
//
#include <hip/hip_runtime.h>
#include <math.h>

#define BATCH 32
#define NSAMP 262144
#define NKNOT 256
#define EPSV  0.001f
#define CH    16                  // samples per chunk = 64 B = one cache line
#define CPB   256                 // chunks per agg-block
#define NCROW (NSAMP / CH)        // 16384 chunks per row
#define BPR   (NCROW / CPB)       // 64 agg-blocks per row (one wave scans it)
#define NB    (BATCH * NCROW / CPB)  // 2048 agg-blocks
#define TC    (BATCH * NCROW)     // 524288 chunks total
#define NWAVE (CPB / 64)          // 4 waves per block

__device__ __forceinline__ float fast_tanh(float x) {
    // tanh(x) = 1 - 2/(exp(2x)+1); branch-free, ~1e-7 abs error
    float e = __expf(2.0f * x);
    float r = __builtin_amdgcn_rcpf(e + 1.0f);
    return fmaf(-2.0f, r, 1.0f);
}

// ---------------------------------------------------------------------------
// Kernel 1: ONE workgroup = TWO agg-blocks (2B, 2B+1). Build phase interleaves
// the two independent 16-sample chains (ILP-2 on the latency-critical path);
// the two wave scans then run R11's exact per-block code -> Cb/G bit-identical.
// ---------------------------------------------------------------------------
__global__ __launch_bounds__(256, 3) void k_agg(
    const float* __restrict__ x,
    const float* __restrict__ cl,     // [BATCH][NKNOT][5]
    float* __restrict__ Cb,           // [6][TC]
    float* __restrict__ G)            // [6][NB]
{
    __shared__ float wag[2][NWAVE][6];
    const int tid = threadIdx.x;
    const int B = blockIdx.x;         // dual-block index
    const int lane = tid & 63, wid = tid >> 6;
    const int b0 = 2 * B, b1 = 2 * B + 1;
    const int cA = b0 * CPB + tid;    // chunk in agg-block b0
    const int cB = b1 * CPB + tid;    // chunk in agg-block b1 (= cA + 256)

    const float4* xpA = (const float4*)(x + (size_t)cA * CH);
    const float4* xpB = (const float4*)(x + (size_t)cB * CH);

    // knot coefficients (channels 0,1) for both chunks (same row)
    const float scale = 255.0f / 262143.0f;
    int r = cA >> 14;
    const float* kb = cl + (size_t)r * NKNOT * 5;

    int colA = cA & (NCROW - 1);
    float posA = (float)(colA * CH) * scale;
    float fiA = floorf(posA);
    int iA0 = (int)fiA;
    float wA0 = posA - fiA;
    int iA1 = min(iA0 + 1, NKNOT - 1), iA2 = min(iA0 + 2, NKNOT - 1);
    float A_k00 = kb[iA0*5+0], A_k01 = kb[iA1*5+0], A_k02 = kb[iA2*5+0];
    float A_k10 = kb[iA0*5+1], A_k11 = kb[iA1*5+1], A_k12 = kb[iA2*5+1];
    float A_d0A = A_k01-A_k00, A_d0B = A_k02-A_k01;
    float A_d1A = A_k11-A_k10, A_d1B = A_k12-A_k11;

    int colB = cB & (NCROW - 1);
    float posB = (float)(colB * CH) * scale;
    float fiB = floorf(posB);
    int iB0 = (int)fiB;
    float wB0 = posB - fiB;
    int iB1 = min(iB0 + 1, NKNOT - 1), iB2 = min(iB0 + 2, NKNOT - 1);
    float B_k00 = kb[iB0*5+0], B_k01 = kb[iB1*5+0], B_k02 = kb[iB2*5+0];
    float B_k10 = kb[iB0*5+1], B_k11 = kb[iB1*5+1], B_k12 = kb[iB2*5+1];
    float B_d0A = B_k01-B_k00, B_d0B = B_k02-B_k01;
    float B_d1A = B_k11-B_k10, B_d1B = B_k12-B_k11;

    // ---- build phase: two independent chains interleaved (ILP-2) ----
    const float stab = 1.0f - EPSV, stab2 = 2.0f * stab;
    float pA1 = 0.f, pA2 = 0.f, mA1 = 1.f, mA2 = 0.f, nA1 = 0.f, nA2 = 1.f;
    float pB1 = 0.f, pB2 = 0.f, mB1 = 1.f, mB2 = 0.f, nB1 = 0.f, nB2 = 1.f;
    #pragma unroll
    for (int v4 = 0; v4 < 4; ++v4) {
        float4 xqa = xpA[v4];
        float4 xqb = xpB[v4];
        #pragma unroll
        for (int q = 0; q < 4; ++q) {
            int j = v4 * 4 + q;
            {   // set A sample (identical op order to R11's build)
                float w = fmaf((float)j, scale, wA0);
                bool sel = w >= 1.0f;
                float wu = sel ? w - 1.0f : w;
                float l0 = fmaf(wu, sel ? A_d0B : A_d0A, sel ? A_k01 : A_k00);
                float l1 = fmaf(wu, sel ? A_d1B : A_d1A, sel ? A_k11 : A_k10);
                float a1 = stab2 * fast_tanh(l0);
                float a1a = fabsf(a1);
                float a2 = 0.5f * fmaf((2.0f - a1a) * stab, fast_tanh(l1), a1a);
                float p  = fmaf(-a2, pA2, (&xqa.x)[q]);  p = fmaf(-a1, pA1, p);
                float hA = fmaf(-a1, mA1, -a2 * mA2);
                float hB = fmaf(-a1, nA1, -a2 * nA2);
                pA2 = pA1; pA1 = p;
                mA2 = mA1; mA1 = hA;
                nA2 = nA1; nA1 = hB;
            }
            {   // set B sample (independent chain)
                float w = fmaf((float)j, scale, wB0);
                bool sel = w >= 1.0f;
                float wu = sel ? w - 1.0f : w;
                float l0 = fmaf(wu, sel ? B_d0B : B_d0A, sel ? B_k01 : B_k00);
                float l1 = fmaf(wu, sel ? B_d1B : B_d1A, sel ? B_k11 : B_k10);
                float a1 = stab2 * fast_tanh(l0);
                float a1a = fabsf(a1);
                float a2 = 0.5f * fmaf((2.0f - a1a) * stab, fast_tanh(l1), a1a);
                float p  = fmaf(-a2, pB2, (&xqb.x)[q]);  p = fmaf(-a1, pB1, p);
                float hA = fmaf(-a1, mB1, -a2 * mB2);
                float hB = fmaf(-a1, nB1, -a2 * nB2);
                pB2 = pB1; pB1 = p;
                mB2 = mB1; mB1 = hA;
                nB2 = nB1; nB1 = hB;
            }
        }
    }
    float LA00 = mA1, LA01 = nA1, LA10 = mA2, LA11 = nA2, LAv0 = pA1, LAv1 = pA2;
    float LB00 = mB1, LB01 = nB1, LB10 = mB2, LB11 = nB2, LBv0 = pB1, LBv1 = pB2;

    // ---- wave-inclusive scan, set A (R11's exact op order) ----
    #pragma unroll
    for (int d = 1; d < 64; d <<= 1) {
        float o00 = __shfl_up(LA00, d), o01 = __shfl_up(LA01, d);
        float o10 = __shfl_up(LA10, d), o11 = __shfl_up(LA11, d);
        float ov0 = __shfl_up(LAv0, d), ov1 = __shfl_up(LAv1, d);
        if (lane >= d) {
            float t00 = LA00 * o00 + LA01 * o10;
            float t01 = LA00 * o01 + LA01 * o11;
            float t10 = LA10 * o00 + LA11 * o10;
            float t11 = LA10 * o01 + LA11 * o11;
            float tv0 = fmaf(LA00, ov0, fmaf(LA01, ov1, LAv0));
            float tv1 = fmaf(LA10, ov0, fmaf(LA11, ov1, LAv1));
            LA00 = t00; LA01 = t01; LA10 = t10; LA11 = t11; LAv0 = tv0; LAv1 = tv1;
        }
    }
    // ---- wave-inclusive scan, set B (independent) ----
    #pragma unroll
    for (int d = 1; d < 64; d <<= 1) {
        float o00 = __shfl_up(LB00, d), o01 = __shfl_up(LB01, d);
        float o10 = __shfl_up(LB10, d), o11 = __shfl_up(LB11, d);
        float ov0 = __shfl_up(LBv0, d), ov1 = __shfl_up(LBv1, d);
        if (lane >= d) {
            float t00 = LB00 * o00 + LB01 * o10;
            float t01 = LB00 * o01 + LB01 * o11;
            float t10 = LB10 * o00 + LB11 * o10;
            float t11 = LB10 * o01 + LB11 * o11;
            float tv0 = fmaf(LB00, ov0, fmaf(LB01, ov1, LBv0));
            float tv1 = fmaf(LB10, ov0, fmaf(LB11, ov1, LBv1));
            LB00 = t00; LB01 = t01; LB10 = t10; LB11 = t11; LBv0 = tv0; LBv1 = tv1;
        }
    }
    if (lane == 63) {
        wag[0][wid][0] = LA00; wag[0][wid][1] = LA01; wag[0][wid][2] = LA10;
        wag[0][wid][3] = LA11; wag[0][wid][4] = LAv0; wag[0][wid][5] = LAv1;
        wag[1][wid][0] = LB00; wag[1][wid][1] = LB01; wag[1][wid][2] = LB10;
        wag[1][wid][3] = LB11; wag[1][wid][4] = LBv0; wag[1][wid][5] = LBv1;
    }
    __syncthreads();

    // ---- set A: P-compose, exclusive E, C = E∘P, stores (R11 op order) ----
    {
        float P00 = 1.f, P01 = 0.f, P10 = 0.f, P11 = 1.f, Pv0 = 0.f, Pv1 = 0.f;
        for (int w2 = 0; w2 < wid; ++w2) {
            float a00 = wag[0][w2][0], a01 = wag[0][w2][1], a10 = wag[0][w2][2];
            float a11 = wag[0][w2][3], av0 = wag[0][w2][4], av1 = wag[0][w2][5];
            float t00 = a00 * P00 + a01 * P10;
            float t01 = a00 * P01 + a01 * P11;
            float t10 = a10 * P00 + a11 * P10;
            float t11 = a10 * P01 + a11 * P11;
            float tv0 = fmaf(a00, Pv0, fmaf(a01, Pv1, av0));
            float tv1 = fmaf(a10, Pv0, fmaf(a11, Pv1, av1));
            P00 = t00; P01 = t01; P10 = t10; P11 = t11; Pv0 = tv0; Pv1 = tv1;
        }
        float E00 = __shfl_up(LA00, 1), E01 = __shfl_up(LA01, 1);
        float E10 = __shfl_up(LA10, 1), E11 = __shfl_up(LA11, 1);
        float Ev0 = __shfl_up(LAv0, 1), Ev1 = __shfl_up(LAv1, 1);
        if (lane == 0) { E00 = 1.f; E01 = 0.f; E10 = 0.f; E11 = 1.f; Ev0 = 0.f; Ev1 = 0.f; }
        Cb[0*TC + cA] = E00 * P00 + E01 * P10;
        Cb[1*TC + cA] = E00 * P01 + E01 * P11;
        Cb[2*TC + cA] = E10 * P00 + E11 * P10;
        Cb[3*TC + cA] = E10 * P01 + E11 * P11;
        Cb[4*TC + cA] = fmaf(E00, Pv0, fmaf(E01, Pv1, Ev0));
        Cb[5*TC + cA] = fmaf(E10, Pv0, fmaf(E11, Pv1, Ev1));
        if (tid == CPB - 1) {
            G[0*NB + b0] = LA00 * P00 + LA01 * P10;
            G[1*NB + b0] = LA00 * P01 + LA01 * P11;
            G[2*NB + b0] = LA10 * P00 + LA11 * P10;
            G[3*NB + b0] = LA10 * P01 + LA11 * P11;
            G[4*NB + b0] = fmaf(LA00, Pv0, fmaf(LA01, Pv1, LAv0));
            G[5*NB + b0] = fmaf(LA10, Pv0, fmaf(LA11, Pv1, LAv1));
        }
    }
    // ---- set B: same ----
    {
        float P00 = 1.f, P01 = 0.f, P10 = 0.f, P11 = 1.f, Pv0 = 0.f, Pv1 = 0.f;
        for (int w2 = 0; w2 < wid; ++w2) {
            float a00 = wag[1][w2][0], a01 = wag[1][w2][1], a10 = wag[1][w2][2];
            float a11 = wag[1][w2][3], av0 = wag[1][w2][4], av1 = wag[1][w2][5];
            float t00 = a00 * P00 + a01 * P10;
            float t01 = a00 * P01 + a01 * P11;
            float t10 = a10 * P00 + a11 * P10;
            float t11 = a10 * P01 + a11 * P11;
            float tv0 = fmaf(a00, Pv0, fmaf(a01, Pv1, av0));
            float tv1 = fmaf(a10, Pv0, fmaf(a11, Pv1, av1));
            P00 = t00; P01 = t01; P10 = t10; P11 = t11; Pv0 = tv0; Pv1 = tv1;
        }
        float E00 = __shfl_up(LB00, 1), E01 = __shfl_up(LB01, 1);
        float E10 = __shfl_up(LB10, 1), E11 = __shfl_up(LB11, 1);
        float Ev0 = __shfl_up(LBv0, 1), Ev1 = __shfl_up(LBv1, 1);
        if (lane == 0) { E00 = 1.f; E01 = 0.f; E10 = 0.f; E11 = 1.f; Ev0 = 0.f; Ev1 = 0.f; }
        Cb[0*TC + cB] = E00 * P00 + E01 * P10;
        Cb[1*TC + cB] = E00 * P01 + E01 * P11;
        Cb[2*TC + cB] = E10 * P00 + E11 * P10;
        Cb[3*TC + cB] = E10 * P01 + E11 * P11;
        Cb[4*TC + cB] = fmaf(E00, Pv0, fmaf(E01, Pv1, Ev0));
        Cb[5*TC + cB] = fmaf(E10, Pv0, fmaf(E11, Pv1, Ev1));
        if (tid == CPB - 1) {
            G[0*NB + b1] = LB00 * P00 + LB01 * P10;
            G[1*NB + b1] = LB00 * P01 + LB01 * P11;
            G[2*NB + b1] = LB10 * P00 + LB11 * P10;
            G[3*NB + b1] = LB10 * P01 + LB11 * P11;
            G[4*NB + b1] = fmaf(LB00, Pv0, fmaf(LB01, Pv1, LBv0));
            G[5*NB + b1] = fmaf(LB10, Pv0, fmaf(LB11, Pv1, LBv1));
        }
    }
}

// ---------------------------------------------------------------------------
// Kernel 2 (R11-verbatim): row-scan of G (wave 0) + single apply+FIR pass
// ---------------------------------------------------------------------------
__global__ __launch_bounds__(256, 6) void k_apply(
    const float* __restrict__ x,
    const float* __restrict__ cl,
    const float* __restrict__ Cb,     // [6][TC]
    const float* __restrict__ G,      // [6][NB]
    float* __restrict__ out)
{
    __shared__ float sInit[2];
    const int tid = threadIdx.x;
    const int b = blockIdx.x;
    const int lane = tid & 63, wid = tid >> 6;

    // wave 0: scan this row's 64 block aggregates -> block-start state
    if (wid == 0) {
        int rowFirst = b & ~(BPR - 1);
        int k = rowFirst + lane;
        float A00 = G[0*NB + k], A01 = G[1*NB + k], A10 = G[2*NB + k];
        float A11 = G[3*NB + k], Av0 = G[4*NB + k], Av1 = G[5*NB + k];
        #pragma unroll
        for (int d = 1; d < 64; d <<= 1) {
            float o00 = __shfl_up(A00, d), o01 = __shfl_up(A01, d);
            float o10 = __shfl_up(A10, d), o11 = __shfl_up(A11, d);
            float ov0 = __shfl_up(Av0, d), ov1 = __shfl_up(Av1, d);
            if (lane >= d) {
                float n00 = A00 * o00 + A01 * o10;
                float n01 = A00 * o01 + A01 * o11;
                float n10 = A10 * o00 + A11 * o10;
                float n11 = A10 * o01 + A11 * o11;
                float nv0 = fmaf(A00, ov0, fmaf(A01, ov1, Av0));
                float nv1 = fmaf(A10, ov0, fmaf(A11, ov1, Av1));
                A00 = n00; A01 = n01; A10 = n10; A11 = n11; Av0 = nv0; Av1 = nv1;
            }
        }
        int myIdx = b & (BPR - 1);
        int src = (myIdx > 0) ? myIdx - 1 : 0;
        float s0 = __shfl(Av0, src);
        float s1 = __shfl(Av1, src);
        if (lane == 0) {
            sInit[0] = myIdx ? s0 : 0.f;
            sInit[1] = myIdx ? s1 : 0.f;
        }
    }

    // knot coefficients (all 5 channels)
    int chunk = b * CPB + tid;
    int r = chunk >> 14;
    int c = chunk & (NCROW - 1);
    const float scale = 255.0f / 262143.0f;
    float pos0 = (float)(c * CH) * scale;
    float fiA = floorf(pos0);
    int idxA = (int)fiA;
    float w0v = pos0 - fiA;
    const float* kb = cl + (size_t)r * NKNOT * 5;
    int i1 = min(idxA + 1, NKNOT - 1);
    int i2 = min(idxA + 2, NKNOT - 1);
    float k00 = kb[idxA*5+0], k01 = kb[i1*5+0], k02 = kb[i2*5+0];
    float k10 = kb[idxA*5+1], k11 = kb[i1*5+1], k12 = kb[i2*5+1];
    float k20 = kb[idxA*5+2], k21 = kb[i1*5+2], k22 = kb[i2*5+2];
    float k30 = kb[idxA*5+3], k31 = kb[i1*5+3], k32 = kb[i2*5+3];
    float k40 = kb[idxA*5+4], k41 = kb[i1*5+4], k42 = kb[i2*5+4];
    float d0A = k01-k00, d0B = k02-k01;
    float d1A = k11-k10, d1B = k12-k11;
    float d2A = k21-k20, d2B = k22-k21;
    float d3A = k31-k30, d3B = k32-k31;
    float d4A = k41-k40, d4B = k42-k41;

    // per-chunk C (coalesced loads)
    float C00 = Cb[0*TC + chunk], C01 = Cb[1*TC + chunk];
    float C10 = Cb[2*TC + chunk], C11 = Cb[3*TC + chunk];
    float Cv0 = Cb[4*TC + chunk], Cv1 = Cb[5*TC + chunk];

    __syncthreads();
    float s0 = sInit[0], s1 = sInit[1];
    float y1 = fmaf(C00, s0, fmaf(C01, s1, Cv0));
    float y2 = fmaf(C10, s0, fmaf(C11, s1, Cv1));

    // single apply+FIR pass (x consumed inline, out written inline)
    const float stab = 1.0f - EPSV, stab2 = 2.0f * stab;
    const float4* xp = (const float4*)(x + (size_t)chunk * CH);
    float4* op = (float4*)(out + (size_t)chunk * CH);
    #pragma unroll
    for (int v4 = 0; v4 < 4; ++v4) {
        float4 xq = xp[v4];
        float4 ov;
        #pragma unroll
        for (int q = 0; q < 4; ++q) {
            int j = v4 * 4 + q;
            float w = fmaf((float)j, scale, w0v);
            bool sel = w >= 1.0f;
            float wu = sel ? w - 1.0f : w;
            float l0 = fmaf(wu, sel ? d0B : d0A, sel ? k01 : k00);
            float l1 = fmaf(wu, sel ? d1B : d1A, sel ? k11 : k10);
            float b0 = fmaf(wu, sel ? d2B : d2A, sel ? k21 : k20);
            float b1c= fmaf(wu, sel ? d3B : d3A, sel ? k31 : k30);
            float b2c= fmaf(wu, sel ? d4B : d4A, sel ? k41 : k40);
            float a1 = stab2 * fast_tanh(l0);
            float a1a = fabsf(a1);
            float a2 = 0.5f * fmaf((2.0f - a1a) * stab, fast_tanh(l1), a1a);
            float y = fmaf(-a2, y2, (&xq.x)[q]);  y = fmaf(-a1, y1, y);
            (&ov.x)[q] = fmaf(b0, y, fmaf(b1c, y1, b2c * y2));
            y2 = y1; y1 = y;
        }
        op[v4] = ov;
    }
}

extern "C" void kernel_launch(void* const* d_in, const int* in_sizes, int n_in,
                              void* d_out, int out_size, void* d_ws, size_t ws_size,
                              hipStream_t stream) {
    const float* x  = (const float*)d_in[0];   // [32][262144]
    const float* cl = (const float*)d_in[1];   // [32][256][5]
    float* out = (float*)d_out;
    float* Cb = (float*)d_ws;                  // [6][TC] = 12.6 MB
    float* G  = Cb + (size_t)6 * TC;           // [6][NB] = 48 KB

    hipLaunchKernelGGL(k_agg,   dim3(NB / 2), dim3(256), 0, stream, x, cl, Cb, G);
    hipLaunchKernelGGL(k_apply, dim3(NB),     dim3(256), 0, stream, x, cl, Cb, G, out);
}

// Round 16
// 38.579 us; speedup vs baseline: 1.5045x; 1.0571x over previous
//
#include <hip/hip_runtime.h>
#include <math.h>

#define BATCH 32
#define NSAMP 262144
#define NKNOT 256
#define EPSV  0.001f
#define CH    16                  // samples per chunk = 64 B = one cache line
#define CPB   256                 // chunks per agg-block (= k_agg threads)
#define NCROW (NSAMP / CH)        // 16384 chunks per row
#define BPR   (NCROW / CPB)       // 64 agg-blocks per row (one wave scans it)
#define NB    (BATCH * NCROW / CPB)  // 2048 agg-blocks
#define TC    (BATCH * NCROW)     // 524288 chunks total
#define NWAVE (CPB / 64)          // 4 waves per block

__device__ __forceinline__ float fast_tanh(float x) {
    // tanh(x) = 1 - 2/(exp(2x)+1); branch-free, ~1e-7 abs error
    float e = __expf(2.0f * x);
    float r = __builtin_amdgcn_rcpf(e + 1.0f);
    return fmaf(-2.0f, r, 1.0f);
}

// ---------------------------------------------------------------------------
// Kernel 1 (R11-identical): per-chunk exclusive in-block prefix C + block G
// ---------------------------------------------------------------------------
__global__ __launch_bounds__(256, 4) void k_agg(
    const float* __restrict__ x,
    const float* __restrict__ cl,     // [BATCH][NKNOT][5]
    float* __restrict__ Cb,           // [6][TC]
    float* __restrict__ G)            // [6][NB]
{
    __shared__ float wag[NWAVE][6];
    const int tid = threadIdx.x;
    const int b = blockIdx.x;
    const int lane = tid & 63, wid = tid >> 6;

    int chunk = b * CPB + tid;
    const float4* xp = (const float4*)(x + (size_t)chunk * CH);

    // knot coefficients (channels 0,1)
    int r = chunk >> 14;                 // / NCROW
    int c = chunk & (NCROW - 1);
    const float scale = 255.0f / 262143.0f;
    float pos0 = (float)(c * CH) * scale;
    float fiA = floorf(pos0);
    int idxA = (int)fiA;
    float w0v = pos0 - fiA;
    const float* kb = cl + (size_t)r * NKNOT * 5;
    int i1 = min(idxA + 1, NKNOT - 1);
    int i2 = min(idxA + 2, NKNOT - 1);
    float k00 = kb[idxA*5+0], k01 = kb[i1*5+0], k02 = kb[i2*5+0];
    float k10 = kb[idxA*5+1], k11 = kb[i1*5+1], k12 = kb[i2*5+1];
    float d0A = k01-k00, d0B = k02-k01;
    float d1A = k11-k10, d1B = k12-k11;

    // build per-chunk affine map  s_end = M s_start + v (consume x inline)
    const float stab = 1.0f - EPSV, stab2 = 2.0f * stab;
    float p1 = 0.f, p2 = 0.f, A1 = 1.f, A2 = 0.f, B1 = 0.f, B2 = 1.f;
    #pragma unroll
    for (int v4 = 0; v4 < 4; ++v4) {
        float4 xq = xp[v4];
        #pragma unroll
        for (int q = 0; q < 4; ++q) {
            int j = v4 * 4 + q;
            float w = fmaf((float)j, scale, w0v);
            bool sel = w >= 1.0f;
            float wu = sel ? w - 1.0f : w;
            float l0 = fmaf(wu, sel ? d0B : d0A, sel ? k01 : k00);
            float l1 = fmaf(wu, sel ? d1B : d1A, sel ? k11 : k10);
            float a1 = stab2 * fast_tanh(l0);
            float a1a = fabsf(a1);
            float a2 = 0.5f * fmaf((2.0f - a1a) * stab, fast_tanh(l1), a1a);
            float p  = fmaf(-a2, p2, (&xq.x)[q]);  p = fmaf(-a1, p1, p);
            float hA = fmaf(-a1, A1, -a2 * A2);
            float hB = fmaf(-a1, B1, -a2 * B2);
            p2 = p1; p1 = p;
            A2 = A1; A1 = hA;
            B2 = B1; B1 = hB;
        }
    }
    float L00 = A1, L01 = B1, L10 = A2, L11 = B2, Lv0 = p1, Lv1 = p2;

    // wave-inclusive scan (compose later ∘ earlier)
    #pragma unroll
    for (int d = 1; d < 64; d <<= 1) {
        float o00 = __shfl_up(L00, d), o01 = __shfl_up(L01, d);
        float o10 = __shfl_up(L10, d), o11 = __shfl_up(L11, d);
        float ov0 = __shfl_up(Lv0, d), ov1 = __shfl_up(Lv1, d);
        if (lane >= d) {
            float n00 = L00 * o00 + L01 * o10;
            float n01 = L00 * o01 + L01 * o11;
            float n10 = L10 * o00 + L11 * o10;
            float n11 = L10 * o01 + L11 * o11;
            float nv0 = fmaf(L00, ov0, fmaf(L01, ov1, Lv0));
            float nv1 = fmaf(L10, ov0, fmaf(L11, ov1, Lv1));
            L00 = n00; L01 = n01; L10 = n10; L11 = n11; Lv0 = nv0; Lv1 = nv1;
        }
    }
    if (lane == 63) {
        wag[wid][0] = L00; wag[wid][1] = L01; wag[wid][2] = L10;
        wag[wid][3] = L11; wag[wid][4] = Lv0; wag[wid][5] = Lv1;
    }
    __syncthreads();

    // P = compose of earlier waves' aggregates
    float P00 = 1.f, P01 = 0.f, P10 = 0.f, P11 = 1.f, Pv0 = 0.f, Pv1 = 0.f;
    for (int w2 = 0; w2 < wid; ++w2) {
        float a00 = wag[w2][0], a01 = wag[w2][1], a10 = wag[w2][2];
        float a11 = wag[w2][3], av0 = wag[w2][4], av1 = wag[w2][5];
        float n00 = a00 * P00 + a01 * P10;
        float n01 = a00 * P01 + a01 * P11;
        float n10 = a10 * P00 + a11 * P10;
        float n11 = a10 * P01 + a11 * P11;
        float nv0 = fmaf(a00, Pv0, fmaf(a01, Pv1, av0));
        float nv1 = fmaf(a10, Pv0, fmaf(a11, Pv1, av1));
        P00 = n00; P01 = n01; P10 = n10; P11 = n11; Pv0 = nv0; Pv1 = nv1;
    }
    // in-wave exclusive E; C = E ∘ P (exclusive prefix from block start)
    float E00 = __shfl_up(L00, 1), E01 = __shfl_up(L01, 1);
    float E10 = __shfl_up(L10, 1), E11 = __shfl_up(L11, 1);
    float Ev0 = __shfl_up(Lv0, 1), Ev1 = __shfl_up(Lv1, 1);
    if (lane == 0) { E00 = 1.f; E01 = 0.f; E10 = 0.f; E11 = 1.f; Ev0 = 0.f; Ev1 = 0.f; }
    Cb[0*TC + chunk] = E00 * P00 + E01 * P10;
    Cb[1*TC + chunk] = E00 * P01 + E01 * P11;
    Cb[2*TC + chunk] = E10 * P00 + E11 * P10;
    Cb[3*TC + chunk] = E10 * P01 + E11 * P11;
    Cb[4*TC + chunk] = fmaf(E00, Pv0, fmaf(E01, Pv1, Ev0));
    Cb[5*TC + chunk] = fmaf(E10, Pv0, fmaf(E11, Pv1, Ev1));

    // block aggregate G = L(tid=255) ∘ P
    if (tid == CPB - 1) {
        G[0*NB + b] = L00 * P00 + L01 * P10;
        G[1*NB + b] = L00 * P01 + L01 * P11;
        G[2*NB + b] = L10 * P00 + L11 * P10;
        G[3*NB + b] = L10 * P01 + L11 * P11;
        G[4*NB + b] = fmaf(L00, Pv0, fmaf(L01, Pv1, Lv0));
        G[5*NB + b] = fmaf(L10, Pv0, fmaf(L11, Pv1, Lv1));
    }
}

// ---------------------------------------------------------------------------
// Kernel 2 (R11 code; launch bound (256,3) so the allocator doesn't spill)
// ---------------------------------------------------------------------------
__global__ __launch_bounds__(256, 3) void k_apply(
    const float* __restrict__ x,
    const float* __restrict__ cl,
    const float* __restrict__ Cb,     // [6][TC]
    const float* __restrict__ G,      // [6][NB]
    float* __restrict__ out)
{
    __shared__ float sInit[2];
    const int tid = threadIdx.x;
    const int b = blockIdx.x;
    const int lane = tid & 63, wid = tid >> 6;

    // wave 0: scan this row's 64 block aggregates -> block-start state
    if (wid == 0) {
        int rowFirst = b & ~(BPR - 1);
        int k = rowFirst + lane;
        float A00 = G[0*NB + k], A01 = G[1*NB + k], A10 = G[2*NB + k];
        float A11 = G[3*NB + k], Av0 = G[4*NB + k], Av1 = G[5*NB + k];
        #pragma unroll
        for (int d = 1; d < 64; d <<= 1) {
            float o00 = __shfl_up(A00, d), o01 = __shfl_up(A01, d);
            float o10 = __shfl_up(A10, d), o11 = __shfl_up(A11, d);
            float ov0 = __shfl_up(Av0, d), ov1 = __shfl_up(Av1, d);
            if (lane >= d) {
                float n00 = A00 * o00 + A01 * o10;
                float n01 = A00 * o01 + A01 * o11;
                float n10 = A10 * o00 + A11 * o10;
                float n11 = A10 * o01 + A11 * o11;
                float nv0 = fmaf(A00, ov0, fmaf(A01, ov1, Av0));
                float nv1 = fmaf(A10, ov0, fmaf(A11, ov1, Av1));
                A00 = n00; A01 = n01; A10 = n10; A11 = n11; Av0 = nv0; Av1 = nv1;
            }
        }
        int myIdx = b & (BPR - 1);
        int src = (myIdx > 0) ? myIdx - 1 : 0;
        float s0 = __shfl(Av0, src);
        float s1 = __shfl(Av1, src);
        if (lane == 0) {
            sInit[0] = myIdx ? s0 : 0.f;
            sInit[1] = myIdx ? s1 : 0.f;
        }
    }

    // knot coefficients (all 5 channels)
    int chunk = b * CPB + tid;
    int r = chunk >> 14;
    int c = chunk & (NCROW - 1);
    const float scale = 255.0f / 262143.0f;
    float pos0 = (float)(c * CH) * scale;
    float fiA = floorf(pos0);
    int idxA = (int)fiA;
    float w0v = pos0 - fiA;
    const float* kb = cl + (size_t)r * NKNOT * 5;
    int i1 = min(idxA + 1, NKNOT - 1);
    int i2 = min(idxA + 2, NKNOT - 1);
    float k00 = kb[idxA*5+0], k01 = kb[i1*5+0], k02 = kb[i2*5+0];
    float k10 = kb[idxA*5+1], k11 = kb[i1*5+1], k12 = kb[i2*5+1];
    float k20 = kb[idxA*5+2], k21 = kb[i1*5+2], k22 = kb[i2*5+2];
    float k30 = kb[idxA*5+3], k31 = kb[i1*5+3], k32 = kb[i2*5+3];
    float k40 = kb[idxA*5+4], k41 = kb[i1*5+4], k42 = kb[i2*5+4];
    float d0A = k01-k00, d0B = k02-k01;
    float d1A = k11-k10, d1B = k12-k11;
    float d2A = k21-k20, d2B = k22-k21;
    float d3A = k31-k30, d3B = k32-k31;
    float d4A = k41-k40, d4B = k42-k41;

    // per-chunk C (coalesced loads)
    float C00 = Cb[0*TC + chunk], C01 = Cb[1*TC + chunk];
    float C10 = Cb[2*TC + chunk], C11 = Cb[3*TC + chunk];
    float Cv0 = Cb[4*TC + chunk], Cv1 = Cb[5*TC + chunk];

    __syncthreads();
    float s0 = sInit[0], s1 = sInit[1];
    float y1 = fmaf(C00, s0, fmaf(C01, s1, Cv0));
    float y2 = fmaf(C10, s0, fmaf(C11, s1, Cv1));

    // single apply+FIR pass (x consumed inline, out written inline)
    const float stab = 1.0f - EPSV, stab2 = 2.0f * stab;
    const float4* xp = (const float4*)(x + (size_t)chunk * CH);
    float4* op = (float4*)(out + (size_t)chunk * CH);
    #pragma unroll
    for (int v4 = 0; v4 < 4; ++v4) {
        float4 xq = xp[v4];
        float4 ov;
        #pragma unroll
        for (int q = 0; q < 4; ++q) {
            int j = v4 * 4 + q;
            float w = fmaf((float)j, scale, w0v);
            bool sel = w >= 1.0f;
            float wu = sel ? w - 1.0f : w;
            float l0 = fmaf(wu, sel ? d0B : d0A, sel ? k01 : k00);
            float l1 = fmaf(wu, sel ? d1B : d1A, sel ? k11 : k10);
            float b0 = fmaf(wu, sel ? d2B : d2A, sel ? k21 : k20);
            float b1c= fmaf(wu, sel ? d3B : d3A, sel ? k31 : k30);
            float b2c= fmaf(wu, sel ? d4B : d4A, sel ? k41 : k40);
            float a1 = stab2 * fast_tanh(l0);
            float a1a = fabsf(a1);
            float a2 = 0.5f * fmaf((2.0f - a1a) * stab, fast_tanh(l1), a1a);
            float y = fmaf(-a2, y2, (&xq.x)[q]);  y = fmaf(-a1, y1, y);
            (&ov.x)[q] = fmaf(b0, y, fmaf(b1c, y1, b2c * y2));
            y2 = y1; y1 = y;
        }
        op[v4] = ov;
    }
}

extern "C" void kernel_launch(void* const* d_in, const int* in_sizes, int n_in,
                              void* d_out, int out_size, void* d_ws, size_t ws_size,
                              hipStream_t stream) {
    const float* x  = (const float*)d_in[0];   // [32][262144]
    const float* cl = (const float*)d_in[1];   // [32][256][5]
    float* out = (float*)d_out;
    float* Cb = (float*)d_ws;                  // [6][TC] = 12.6 MB
    float* G  = Cb + (size_t)6 * TC;           // [6][NB] = 48 KB

    hipLaunchKernelGGL(k_agg,   dim3(NB), dim3(CPB), 0, stream, x, cl, Cb, G);
    hipLaunchKernelGGL(k_apply, dim3(NB), dim3(CPB), 0, stream, x, cl, Cb, G, out);
}

// Round 18
// 38.350 us; speedup vs baseline: 1.5135x; 1.0060x over previous
//
#include <hip/hip_runtime.h>
#include <math.h>

#define BATCH 32
#define NSAMP 262144
#define NKNOT 256
#define EPSV  0.001f
#define CH    16                  // samples per chunk = 64 B = one cache line
#define CPB   256                 // chunks per agg-block (= k_agg threads)
#define NCROW (NSAMP / CH)        // 16384 chunks per row
#define BPR   (NCROW / CPB)       // 64 agg-blocks per row (one wave scans it)
#define NB    (BATCH * NCROW / CPB)  // 2048 agg-blocks
#define TC    (BATCH * NCROW)     // 524288 chunks total
#define NWAVE (CPB / 64)          // 4 waves per block

__device__ __forceinline__ float fast_tanh(float x) {
    // tanh(x) = 1 - 2/(exp(2x)+1); branch-free, ~1e-7 abs error
    float e = __expf(2.0f * x);
    float r = __builtin_amdgcn_rcpf(e + 1.0f);
    return fmaf(-2.0f, r, 1.0f);
}

// ---------------------------------------------------------------------------
// Kernel 1 (R11 math, (256,3) so the allocator doesn't spill):
// per-chunk exclusive in-block prefix C + block aggregate G
// ---------------------------------------------------------------------------
__global__ __launch_bounds__(256, 3) void k_agg(
    const float* __restrict__ x,
    const float* __restrict__ cl,     // [BATCH][NKNOT][5]
    float* __restrict__ Cb,           // [6][TC]
    float* __restrict__ G)            // [6][NB]
{
    __shared__ float wag[NWAVE][6];
    const int tid = threadIdx.x;
    const int b = blockIdx.x;
    const int lane = tid & 63, wid = tid >> 6;

    int chunk = b * CPB + tid;
    const float4* xp = (const float4*)(x + (size_t)chunk * CH);

    // knot coefficients (channels 0,1)
    int r = chunk >> 14;                 // / NCROW
    int c = chunk & (NCROW - 1);
    const float scale = 255.0f / 262143.0f;
    float pos0 = (float)(c * CH) * scale;
    float fiA = floorf(pos0);
    int idxA = (int)fiA;
    float w0v = pos0 - fiA;
    const float* kb = cl + (size_t)r * NKNOT * 5;
    int i1 = min(idxA + 1, NKNOT - 1);
    int i2 = min(idxA + 2, NKNOT - 1);
    float k00 = kb[idxA*5+0], k01 = kb[i1*5+0], k02 = kb[i2*5+0];
    float k10 = kb[idxA*5+1], k11 = kb[i1*5+1], k12 = kb[i2*5+1];
    float d0A = k01-k00, d0B = k02-k01;
    float d1A = k11-k10, d1B = k12-k11;

    // build per-chunk affine map  s_end = M s_start + v (consume x inline)
    const float stab = 1.0f - EPSV, stab2 = 2.0f * stab;
    float p1 = 0.f, p2 = 0.f, A1 = 1.f, A2 = 0.f, B1 = 0.f, B2 = 1.f;
    #pragma unroll
    for (int v4 = 0; v4 < 4; ++v4) {
        float4 xq = xp[v4];
        #pragma unroll
        for (int q = 0; q < 4; ++q) {
            int j = v4 * 4 + q;
            float w = fmaf((float)j, scale, w0v);
            bool sel = w >= 1.0f;
            float wu = sel ? w - 1.0f : w;
            float l0 = fmaf(wu, sel ? d0B : d0A, sel ? k01 : k00);
            float l1 = fmaf(wu, sel ? d1B : d1A, sel ? k11 : k10);
            float a1 = stab2 * fast_tanh(l0);
            float a1a = fabsf(a1);
            float a2 = 0.5f * fmaf((2.0f - a1a) * stab, fast_tanh(l1), a1a);
            float p  = fmaf(-a2, p2, (&xq.x)[q]);  p = fmaf(-a1, p1, p);
            float hA = fmaf(-a1, A1, -a2 * A2);
            float hB = fmaf(-a1, B1, -a2 * B2);
            p2 = p1; p1 = p;
            A2 = A1; A1 = hA;
            B2 = B1; B1 = hB;
        }
    }
    float L00 = A1, L01 = B1, L10 = A2, L11 = B2, Lv0 = p1, Lv1 = p2;

    // wave-inclusive scan (compose later ∘ earlier)
    #pragma unroll
    for (int d = 1; d < 64; d <<= 1) {
        float o00 = __shfl_up(L00, d), o01 = __shfl_up(L01, d);
        float o10 = __shfl_up(L10, d), o11 = __shfl_up(L11, d);
        float ov0 = __shfl_up(Lv0, d), ov1 = __shfl_up(Lv1, d);
        if (lane >= d) {
            float n00 = L00 * o00 + L01 * o10;
            float n01 = L00 * o01 + L01 * o11;
            float n10 = L10 * o00 + L11 * o10;
            float n11 = L10 * o01 + L11 * o11;
            float nv0 = fmaf(L00, ov0, fmaf(L01, ov1, Lv0));
            float nv1 = fmaf(L10, ov0, fmaf(L11, ov1, Lv1));
            L00 = n00; L01 = n01; L10 = n10; L11 = n11; Lv0 = nv0; Lv1 = nv1;
        }
    }
    if (lane == 63) {
        wag[wid][0] = L00; wag[wid][1] = L01; wag[wid][2] = L10;
        wag[wid][3] = L11; wag[wid][4] = Lv0; wag[wid][5] = Lv1;
    }
    __syncthreads();

    // P = compose of earlier waves' aggregates
    float P00 = 1.f, P01 = 0.f, P10 = 0.f, P11 = 1.f, Pv0 = 0.f, Pv1 = 0.f;
    for (int w2 = 0; w2 < wid; ++w2) {
        float a00 = wag[w2][0], a01 = wag[w2][1], a10 = wag[w2][2];
        float a11 = wag[w2][3], av0 = wag[w2][4], av1 = wag[w2][5];
        float n00 = a00 * P00 + a01 * P10;
        float n01 = a00 * P01 + a01 * P11;
        float n10 = a10 * P00 + a11 * P10;
        float n11 = a10 * P01 + a11 * P11;
        float nv0 = fmaf(a00, Pv0, fmaf(a01, Pv1, av0));
        float nv1 = fmaf(a10, Pv0, fmaf(a11, Pv1, av1));
        P00 = n00; P01 = n01; P10 = n10; P11 = n11; Pv0 = nv0; Pv1 = nv1;
    }
    // in-wave exclusive E; C = E ∘ P (exclusive prefix from block start)
    float E00 = __shfl_up(L00, 1), E01 = __shfl_up(L01, 1);
    float E10 = __shfl_up(L10, 1), E11 = __shfl_up(L11, 1);
    float Ev0 = __shfl_up(Lv0, 1), Ev1 = __shfl_up(Lv1, 1);
    if (lane == 0) { E00 = 1.f; E01 = 0.f; E10 = 0.f; E11 = 1.f; Ev0 = 0.f; Ev1 = 0.f; }
    Cb[0*TC + chunk] = E00 * P00 + E01 * P10;
    Cb[1*TC + chunk] = E00 * P01 + E01 * P11;
    Cb[2*TC + chunk] = E10 * P00 + E11 * P10;
    Cb[3*TC + chunk] = E10 * P01 + E11 * P11;
    Cb[4*TC + chunk] = fmaf(E00, Pv0, fmaf(E01, Pv1, Ev0));
    Cb[5*TC + chunk] = fmaf(E10, Pv0, fmaf(E11, Pv1, Ev1));

    // block aggregate G = L(tid=255) ∘ P
    if (tid == CPB - 1) {
        G[0*NB + b] = L00 * P00 + L01 * P10;
        G[1*NB + b] = L00 * P01 + L01 * P11;
        G[2*NB + b] = L10 * P00 + L11 * P10;
        G[3*NB + b] = L10 * P01 + L11 * P11;
        G[4*NB + b] = fmaf(L00, Pv0, fmaf(L01, Pv1, Lv0));
        G[5*NB + b] = fmaf(L10, Pv0, fmaf(L11, Pv1, Lv1));
    }
}

// ---------------------------------------------------------------------------
// Kernel 2 (R16-identical): row-scan of G (wave 0) + single apply+FIR pass
// ---------------------------------------------------------------------------
__global__ __launch_bounds__(256, 3) void k_apply(
    const float* __restrict__ x,
    const float* __restrict__ cl,
    const float* __restrict__ Cb,     // [6][TC]
    const float* __restrict__ G,      // [6][NB]
    float* __restrict__ out)
{
    __shared__ float sInit[2];
    const int tid = threadIdx.x;
    const int b = blockIdx.x;
    const int lane = tid & 63, wid = tid >> 6;

    // wave 0: scan this row's 64 block aggregates -> block-start state
    if (wid == 0) {
        int rowFirst = b & ~(BPR - 1);
        int k = rowFirst + lane;
        float A00 = G[0*NB + k], A01 = G[1*NB + k], A10 = G[2*NB + k];
        float A11 = G[3*NB + k], Av0 = G[4*NB + k], Av1 = G[5*NB + k];
        #pragma unroll
        for (int d = 1; d < 64; d <<= 1) {
            float o00 = __shfl_up(A00, d), o01 = __shfl_up(A01, d);
            float o10 = __shfl_up(A10, d), o11 = __shfl_up(A11, d);
            float ov0 = __shfl_up(Av0, d), ov1 = __shfl_up(Av1, d);
            if (lane >= d) {
                float n00 = A00 * o00 + A01 * o10;
                float n01 = A00 * o01 + A01 * o11;
                float n10 = A10 * o00 + A11 * o10;
                float n11 = A10 * o01 + A11 * o11;
                float nv0 = fmaf(A00, ov0, fmaf(A01, ov1, Av0));
                float nv1 = fmaf(A10, ov0, fmaf(A11, ov1, Av1));
                A00 = n00; A01 = n01; A10 = n10; A11 = n11; Av0 = nv0; Av1 = nv1;
            }
        }
        int myIdx = b & (BPR - 1);
        int src = (myIdx > 0) ? myIdx - 1 : 0;
        float s0 = __shfl(Av0, src);
        float s1 = __shfl(Av1, src);
        if (lane == 0) {
            sInit[0] = myIdx ? s0 : 0.f;
            sInit[1] = myIdx ? s1 : 0.f;
        }
    }

    // knot coefficients (all 5 channels)
    int chunk = b * CPB + tid;
    int r = chunk >> 14;
    int c = chunk & (NCROW - 1);
    const float scale = 255.0f / 262143.0f;
    float pos0 = (float)(c * CH) * scale;
    float fiA = floorf(pos0);
    int idxA = (int)fiA;
    float w0v = pos0 - fiA;
    const float* kb = cl + (size_t)r * NKNOT * 5;
    int i1 = min(idxA + 1, NKNOT - 1);
    int i2 = min(idxA + 2, NKNOT - 1);
    float k00 = kb[idxA*5+0], k01 = kb[i1*5+0], k02 = kb[i2*5+0];
    float k10 = kb[idxA*5+1], k11 = kb[i1*5+1], k12 = kb[i2*5+1];
    float k20 = kb[idxA*5+2], k21 = kb[i1*5+2], k22 = kb[i2*5+2];
    float k30 = kb[idxA*5+3], k31 = kb[i1*5+3], k32 = kb[i2*5+3];
    float k40 = kb[idxA*5+4], k41 = kb[i1*5+4], k42 = kb[i2*5+4];
    float d0A = k01-k00, d0B = k02-k01;
    float d1A = k11-k10, d1B = k12-k11;
    float d2A = k21-k20, d2B = k22-k21;
    float d3A = k31-k30, d3B = k32-k31;
    float d4A = k41-k40, d4B = k42-k41;

    // per-chunk C (coalesced loads)
    float C00 = Cb[0*TC + chunk], C01 = Cb[1*TC + chunk];
    float C10 = Cb[2*TC + chunk], C11 = Cb[3*TC + chunk];
    float Cv0 = Cb[4*TC + chunk], Cv1 = Cb[5*TC + chunk];

    __syncthreads();
    float s0 = sInit[0], s1 = sInit[1];
    float y1 = fmaf(C00, s0, fmaf(C01, s1, Cv0));
    float y2 = fmaf(C10, s0, fmaf(C11, s1, Cv1));

    // single apply+FIR pass (x consumed inline, out written inline)
    const float stab = 1.0f - EPSV, stab2 = 2.0f * stab;
    const float4* xp = (const float4*)(x + (size_t)chunk * CH);
    float4* op = (float4*)(out + (size_t)chunk * CH);
    #pragma unroll
    for (int v4 = 0; v4 < 4; ++v4) {
        float4 xq = xp[v4];
        float4 ov;
        #pragma unroll
        for (int q = 0; q < 4; ++q) {
            int j = v4 * 4 + q;
            float w = fmaf((float)j, scale, w0v);
            bool sel = w >= 1.0f;
            float wu = sel ? w - 1.0f : w;
            float l0 = fmaf(wu, sel ? d0B : d0A, sel ? k01 : k00);
            float l1 = fmaf(wu, sel ? d1B : d1A, sel ? k11 : k10);
            float b0 = fmaf(wu, sel ? d2B : d2A, sel ? k21 : k20);
            float b1c= fmaf(wu, sel ? d3B : d3A, sel ? k31 : k30);
            float b2c= fmaf(wu, sel ? d4B : d4A, sel ? k41 : k40);
            float a1 = stab2 * fast_tanh(l0);
            float a1a = fabsf(a1);
            float a2 = 0.5f * fmaf((2.0f - a1a) * stab, fast_tanh(l1), a1a);
            float y = fmaf(-a2, y2, (&xq.x)[q]);  y = fmaf(-a1, y1, y);
            (&ov.x)[q] = fmaf(b0, y, fmaf(b1c, y1, b2c * y2));
            y2 = y1; y1 = y;
        }
        op[v4] = ov;
    }
}

extern "C" void kernel_launch(void* const* d_in, const int* in_sizes, int n_in,
                              void* d_out, int out_size, void* d_ws, size_t ws_size,
                              hipStream_t stream) {
    const float* x  = (const float*)d_in[0];   // [32][262144]
    const float* cl = (const float*)d_in[1];   // [32][256][5]
    float* out = (float*)d_out;
    float* Cb = (float*)d_ws;                  // [6][TC] = 12.6 MB
    float* G  = Cb + (size_t)6 * TC;           // [6][NB] = 48 KB

    hipLaunchKernelGGL(k_agg,   dim3(NB), dim3(CPB), 0, stream, x, cl, Cb, G);
    hipLaunchKernelGGL(k_apply, dim3(NB), dim3(CPB), 0, stream, x, cl, Cb, G, out);
}